// Round 2
// baseline (135.707 us; speedup 1.0000x reference)
//
#include <hip/hip_runtime.h>

#define NSAMP   20
#define BROWS   65536
#define RPB     8                     // rows per block
#define BLOCK   320                   // 5 waves; 8 rows x 40 samples = 320 tasks
#define NBLOCKS (BROWS / RPB)         // 8192

// One block = 8 rows. Stage both tensors' rows into LDS de-interleaved
// (knots separate from coeff float2 pairs), then one thread per
// (row, sample, pred|true) task. Partner exchange via __shfl(lane^32).
__global__ __launch_bounds__(BLOCK) void bspline_loss_main(
    const float* __restrict__ pred, const float* __restrict__ tru,
    float* __restrict__ partials)
{
    __shared__ float  kn[RPB][2][65];   // +1 pad: slice bases differ mod 32 banks
    __shared__ float2 cf[RPB][2][64];
    __shared__ float  wpart[BLOCK / 64];

    const int tid = threadIdx.x;
    const size_t base = (size_t)blockIdx.x * (RPB * 192);

    // ---- stage: de-interleave (knot, cx, cy) triples; rows are contiguous ----
    #pragma unroll
    for (int tz = 0; tz < 2; ++tz) {
        const float* src = (tz ? tru : pred) + base;
        for (int j = tid; j < RPB * 64; j += BLOCK) {   // 512 triples
            const int row = j >> 6, q = j & 63;
            const float k = src[3 * j];
            const float x = src[3 * j + 1];
            const float y = src[3 * j + 2];
            kn[row][tz][q] = k;
            cf[row][tz][q] = make_float2(x, y);
        }
    }
    __syncthreads();

    // ---- task mapping: partner (pred<->true) sits at lane^32 in same wave ----
    const int lane = tid & 63;
    const int wave = tid >> 6;
    const int slot = wave * 32 + (lane & 31);   // 0..159 = row*20 + sample
    const int sel  = lane >> 5;                 // 0 = pred, 1 = true
    const int row  = slot / 20;
    const int s    = slot - row * 20;

    const float*  K = kn[row][sel];
    const float2* C = cf[row][sel];

    // low = kf[3] = 0 always; high = knots[60]
    const float high = K[60];
    const float tv = (float)s * (1.0f / 19.0f) * high;

    // branchless upper_bound over padded 64 knots; reference searches only
    // knots[0..59], results differ only when tv >= knots[60] -> clamp to 60.
    int pos = 0;
    #pragma unroll
    for (int st = 32; st >= 1; st >>= 1)
        pos += (K[pos + st - 1] <= tv) ? st : 0;
    const int cnt = min(pos, 60);

    // kf[cnt+j] for j=1..6, where kf[m] = (m<4) ? 0 : knots[m-4]
    float kfv[7];
    #pragma unroll
    for (int j = 1; j <= 6; ++j) {
        const int idx = cnt + j - 4;            // in [-3, 62]
        const float v = K[idx < 0 ? 0 : idx];
        kfv[j] = (idx < 0) ? 0.f : v;
    }

    float2 p0 = C[cnt], p1 = C[cnt + 1], p2 = C[cnt + 2], p3 = C[cnt + 3];

    // weights are all 1 -> w-channel stays 1 through the recurrence; divide
    // at the end is a no-op. Denominators provably > 0 (kj index >= 4 and
    // knots strictly increasing) -> no guard, rcp-based alpha.
    auto alphaf = [&](float ki, float kj) {
        return (tv - ki) * __builtin_amdgcn_rcpf(kj - ki);
    };
    auto lerp2 = [](float2 a, float2 b, float al) {
        const float bl = 1.0f - al;
        return make_float2(fmaf(al, b.x, bl * a.x), fmaf(al, b.y, bl * a.y));
    };
    // descending k within each level == reference's simultaneous update
    p3 = lerp2(p2, p3, alphaf(kfv[3], kfv[6]));   // l=1,k=3
    p2 = lerp2(p1, p2, alphaf(kfv[2], kfv[5]));   // l=1,k=2
    p1 = lerp2(p0, p1, alphaf(kfv[1], kfv[4]));   // l=1,k=1
    p3 = lerp2(p2, p3, alphaf(kfv[3], kfv[5]));   // l=2,k=3
    p2 = lerp2(p1, p2, alphaf(kfv[2], kfv[4]));   // l=2,k=2
    p3 = lerp2(p2, p3, alphaf(kfv[3], kfv[4]));   // l=3,k=3

    // ---- pair, square, reduce (each pair counted twice -> *0.5 at the end) ----
    const float ox = __shfl(p3.x, lane ^ 32, 64);
    const float oy = __shfl(p3.y, lane ^ 32, 64);
    const float dx = p3.x - ox, dy = p3.y - oy;
    float acc = fmaf(dx, dx, dy * dy);
    #pragma unroll
    for (int off = 32; off >= 1; off >>= 1)
        acc += __shfl_down(acc, off, 64);
    if (lane == 0) wpart[wave] = acc;
    __syncthreads();
    if (tid == 0)
        partials[blockIdx.x] =
            (wpart[0] + wpart[1] + wpart[2] + wpart[3] + wpart[4]) * 0.5f;
}

__global__ __launch_bounds__(256) void bspline_loss_reduce(
    const float* __restrict__ partials, float* __restrict__ out)
{
    const int tid = threadIdx.x;
    double acc = 0.0;
    const float4* p4 = (const float4*)partials;
    #pragma unroll
    for (int i = tid; i < NBLOCKS / 4; i += 256) {    // 2048 float4s, 8/thread
        const float4 v = p4[i];
        acc += (double)((v.x + v.y) + (v.z + v.w));
    }
    #pragma unroll
    for (int off = 32; off >= 1; off >>= 1)
        acc += __shfl_down(acc, off, 64);
    __shared__ double ws[4];
    if ((tid & 63) == 0) ws[tid >> 6] = acc;
    __syncthreads();
    if (tid == 0) {
        const double tot = ws[0] + ws[1] + ws[2] + ws[3];
        out[0] = (float)(tot / (double)((long long)BROWS * NSAMP));
    }
}

extern "C" void kernel_launch(void* const* d_in, const int* in_sizes, int n_in,
                              void* d_out, int out_size, void* d_ws, size_t ws_size,
                              hipStream_t stream) {
    const float* pred = (const float*)d_in[0];
    const float* tru  = (const float*)d_in[1];
    // d_in[2] (true_masks) ignored: reference uses mask = ones.
    float* out      = (float*)d_out;
    float* partials = (float*)d_ws;   // 32 KB

    bspline_loss_main<<<NBLOCKS, BLOCK, 0, stream>>>(pred, tru, partials);
    bspline_loss_reduce<<<1, 256, 0, stream>>>(partials, out);
}